// Round 11
// baseline (215.756 us; speedup 1.0000x reference)
//
// ROUND 11: delete V via S-trick. kvs = (phi_k^T X) @ Wv^T + ksum*bv.
// K1: 1536-col GEMM (q,k,ddq,ddk), writes only phiq+phik (66MB).
// K2 (k_S): S[bh][32][128] from phik + x (L3-hot), register-accumulated MFMA.
// k_fold: S -> kvs -> Gt (f32, broadcast LDS). k_out unchanged (r9-proven).
#include <hip/hip_runtime.h>
#include <cstdint>

typedef __attribute__((ext_vector_type(4))) float f32x4;
typedef __attribute__((ext_vector_type(8))) short short8;
typedef __attribute__((ext_vector_type(8))) unsigned short us8;

#define DEV __device__ __forceinline__

DEV unsigned short f2b(float f) {
  unsigned u = __builtin_bit_cast(unsigned, f);
  return (unsigned short)((u + 0x7fffu + ((u >> 16) & 1u)) >> 16);
}
DEV float b2f(unsigned short h) {
  unsigned u = ((unsigned)h) << 16;
  return __builtin_bit_cast(float, u);
}

constexpr float SQ_SCALE = 0.35355339059327379f;    // 64^-0.25 (tau=1)
constexpr float RATIO    = 0.18257418583505536f;    // 1/sqrt(30)
constexpr float REPS     = 0.18257418583505536e-6f; // RATIO * 1e-6

// B=16, T=4096, N=65536, C_IN=128, H=8, D=64, M=30 (pad 32)
// wqkv cols: [0,512) q | [512,1024) k | [1024,1280) ddq | [1280,1536) ddk
constexpr size_t OF_WQKV = 0;          // 1536*128 bf16 = 393216
constexpr size_t OF_WBP  = 393216;     // 1536 f32 (pad to 8192)
constexpr size_t OF_PHIQ = 401408;     // [8][65536][32] bf16 = 33554432
constexpr size_t OF_PHIK = 33955840;   // [8][65536][32] bf16 = 33554432
constexpr size_t OF_S    = 67510272;   // [128][32][128] f32 = 2097152
constexpr size_t OF_KSUM = 69607424;   // [128][32] f32 = 16384
constexpr size_t OF_GT   = 69623808;   // [128][64][32] bf16 = 524288
constexpr size_t WS_NEED = 70148096;

// ---------------- K0: pack scaled q/k weights + fold proj ----------------
__global__ __launch_bounds__(256) void k_pack(
    const float* __restrict__ wq, const float* __restrict__ wk,
    const float* __restrict__ bq, const float* __restrict__ bk,
    const float* __restrict__ proj,
    unsigned short* __restrict__ wqkv, float* __restrict__ wbp) {
  int bid = blockIdx.x, tid = threadIdx.x;
  if (bid < 512) {
    int id = bid * 256 + tid;            // cols 0..1023 (q then k)
    int c = id >> 7, k = id & 127;
    int mat = c >> 9, row = c & 511;
    const float* w = (mat == 0) ? wq : wk;
    wqkv[id] = f2b(w[row * 128 + k] * SQ_SCALE);
  } else if (bid < 528) {
    __shared__ float wsm[64 * 128];
    __shared__ float ps[32 * 64];
    __shared__ float bs[64];
    int db = bid - 512, mat2 = db >> 3, h = db & 7;
    const float* wsrc = (mat2 == 0) ? wq : wk;
    const float* bsrc = (mat2 == 0) ? bq : bk;
    for (int i = tid; i < 8192; i += 256) wsm[i] = wsrc[h * 8192 + i] * SQ_SCALE;
    for (int i = tid; i < 2048; i += 256) {
      int m = i >> 6, d = i & 63;
      ps[i] = (m < 30) ? proj[m * 64 + d] : 0.0f;
    }
    if (tid < 64) bs[tid] = bsrc[h * 64 + tid] * SQ_SCALE;
    __syncthreads();
    int m = tid >> 3, kseg = tid & 7;
    int col = 1024 + mat2 * 256 + h * 32 + m;
#pragma unroll 4
    for (int kk = 0; kk < 16; ++kk) {
      int k = kseg * 16 + kk;
      float a = 0.f;
      for (int d = 0; d < 64; ++d) a += ps[m * 64 + d] * wsm[d * 128 + k];
      wqkv[col * 128 + k] = f2b(a);
    }
    if (tid < 32) {
      float a = 0.f;
      for (int d = 0; d < 64; ++d) a += ps[tid * 64 + d] * bs[d];
      wbp[1024 + mat2 * 256 + h * 32 + tid] = a;
    }
  } else {
    for (int i = tid; i < 1024; i += 256) {
      int mat = i >> 9, row = i & 511;
      const float* bb = (mat == 0) ? bq : bk;
      wbp[i] = bb[row] * SQ_SCALE;
    }
  }
}

// ---------------- K1: GEMM -> diag, phi_q, phi_k (coalesced) ----------------
__global__ __launch_bounds__(256) void k_qkv(
    const float* __restrict__ x, const unsigned short* __restrict__ wqkv,
    const float* __restrict__ wbp,
    unsigned short* __restrict__ phiq, unsigned short* __restrict__ phik) {
  __shared__ unsigned short xs[64 * 128];      // 16KB swizzled bf16 x-tile
  __shared__ unsigned short scratch[4][2048];  // 4KB per-wave phi stage
  __shared__ float diag_s[2][512];             // [q|k][h*64 + tok]

  int tid = threadIdx.x;
  int w = tid >> 6, l = tid & 63;
  int g = l >> 4, li = l & 15;
  int n0 = blockIdx.x * 64;

  {
    int row = tid >> 2, seg = tid & 3;
    const float* src = x + (size_t)(n0 + row) * 128 + seg * 32;
#pragma unroll
    for (int q8 = 0; q8 < 4; ++q8) {
      f32x4 a = *reinterpret_cast<const f32x4*>(src + q8 * 8);
      f32x4 c = *reinterpret_cast<const f32x4*>(src + q8 * 8 + 4);
      us8 o;
      o[0] = f2b(a[0]); o[1] = f2b(a[1]); o[2] = f2b(a[2]); o[3] = f2b(a[3]);
      o[4] = f2b(c[0]); o[5] = f2b(c[1]); o[6] = f2b(c[2]); o[7] = f2b(c[3]);
      int byte = (row * 256 + seg * 64 + q8 * 16) ^ ((row & 7) << 4);
      *reinterpret_cast<us8*>(((char*)xs) + byte) = o;
    }
  }
  __syncthreads();

  const short* wq_s = reinterpret_cast<const short*>(wqkv);
  char* scr = (char*)scratch[w];

  for (int j = 0; j < 6; ++j) {
    if (j == 4) __syncthreads();   // diag complete before dd tiles
    int tl = j * 4 + w;            // 0-7 q | 8-15 k | 16-19 ddq | 20-23 ddk
    int bcol = tl * 64;

    f32x4 acc[4][4] = {};
#pragma unroll
    for (int ks = 0; ks < 4; ++ks) {
      short8 a[4], bb[4];
#pragma unroll
      for (int fi = 0; fi < 4; ++fi) {
        int tokl = fi * 16 + li;
        int byte = (tokl * 256 + (ks * 32 + g * 8) * 2) ^ ((tokl & 7) << 4);
        a[fi] = *reinterpret_cast<const short8*>(((const char*)xs) + byte);
      }
#pragma unroll
      for (int fj = 0; fj < 4; ++fj)
        bb[fj] = *reinterpret_cast<const short8*>(wq_s + (bcol + fj * 16 + li) * 128 + ks * 32 + g * 8);
#pragma unroll
      for (int fi = 0; fi < 4; ++fi)
#pragma unroll
        for (int fj = 0; fj < 4; ++fj)
          acc[fi][fj] = __builtin_amdgcn_mfma_f32_16x16x32_bf16(a[fi], bb[fj], acc[fi][fj], 0, 0, 0);
    }
#pragma unroll
    for (int fj = 0; fj < 4; ++fj) {
      float bias = wbp[bcol + fj * 16 + li];
#pragma unroll
      for (int fi = 0; fi < 4; ++fi)
#pragma unroll
        for (int r = 0; r < 4; ++r) acc[fi][fj][r] += bias;
    }

    if (j < 4) {
      // q/k tile -> diag = 0.5*sum_d data^2
      int qk = j >> 1;
      int h = tl - qk * 8;
      float t4[4][4];
#pragma unroll
      for (int fi = 0; fi < 4; ++fi)
#pragma unroll
        for (int r = 0; r < 4; ++r) {
          float s = 0.f;
#pragma unroll
          for (int fj = 0; fj < 4; ++fj) { float v = acc[fi][fj][r]; s += v * v; }
          t4[fi][r] = s;
        }
#pragma unroll
      for (int mask = 1; mask <= 8; mask <<= 1)
#pragma unroll
        for (int fi = 0; fi < 4; ++fi)
#pragma unroll
          for (int r = 0; r < 4; ++r)
            t4[fi][r] += __shfl_xor(t4[fi][r], mask, 64);
      if (li == 0) {
#pragma unroll
        for (int fi = 0; fi < 4; ++fi)
#pragma unroll
          for (int r = 0; r < 4; ++r)
            diag_s[qk][h * 64 + fi * 16 + g * 4 + r] = 0.5f * t4[fi][r];
      }
    } else {
      // dd tiles: j==4 -> phi_q, j==5 -> phi_k; wave handles 2 heads
      bool isq = (j == 4);
      unsigned short* dst = isq ? phiq : phik;
      const float* dgrow = diag_s[isq ? 0 : 1];
#pragma unroll
      for (int hp = 0; hp < 2; ++hp) {
        int h = (tl - (isq ? 16 : 20)) * 2 + hp;
#pragma unroll
        for (int fj2 = 0; fj2 < 2; ++fj2) {
          int m = fj2 * 16 + li;
          bool valid = (m < 30);
#pragma unroll
          for (int fi = 0; fi < 4; ++fi)
#pragma unroll
            for (int r = 0; r < 4; ++r) {
              int tok = fi * 16 + g * 4 + r;
              float ph = valid
                  ? (RATIO * __expf(acc[fi][hp * 2 + fj2][r] - dgrow[h * 64 + tok]) + REPS)
                  : 0.0f;
              int byte = (tok * 64 + m * 2) ^ ((tok & 7) << 4);
              *reinterpret_cast<unsigned short*>(scr + byte) = f2b(ph);
            }
        }
        // wave-local LDS RAW; compiler orders via lgkmcnt
        size_t gbase = ((size_t)h * 65536 + n0 + l) * 32;
#pragma unroll
        for (int i = 0; i < 4; ++i) {
          int byte = (l * 64 + i * 16) ^ ((l & 7) << 4);
          us8 o = *reinterpret_cast<const us8*>(scr + byte);
          *reinterpret_cast<us8*>(&dst[gbase + i * 8]) = o;
        }
      }
    }
  }
}

// ---------------- K2: S[bh][m][c] += phi_k^T @ x, ksum += sum phi_k ----------------
__global__ __launch_bounds__(256) void k_S(
    const unsigned short* __restrict__ phik, const float* __restrict__ x,
    float* __restrict__ S, float* __restrict__ ksum) {
  __shared__ unsigned short phit[32 * 64];  // [m][tok] bf16, swizzled
  __shared__ unsigned short xst[128 * 64];  // [c][tok] bf16, swizzled (16KB)
  __shared__ float ksums[32];

  int tid = threadIdx.x;
  int w = tid >> 6, l = tid & 63, g = l >> 4, li = l & 15;
  int bid = blockIdx.x;
  int bh = bid >> 2, chunk = bid & 3;
  int b = bh >> 3, h = bh & 7;
  if (tid < 32) ksums[tid] = 0.f;

  int ptok = tid & 63;
  int mseg = tid >> 6;
  int cgrp = tid & 31, tgrp = tid >> 5;   // x staging: c=cgrp*4.., t=tgrp*8..
  float kpart[8] = {0, 0, 0, 0, 0, 0, 0, 0};
  f32x4 acc[2][2] = {};
  int tok0 = chunk * 1024;

  for (int tile = 0; tile < 16; ++tile) {
    int t0 = tok0 + tile * 64;
    __syncthreads();
    {
      int n = b * 4096 + t0 + ptok;
      us8 p8 = *reinterpret_cast<const us8*>(&phik[((size_t)h * 65536 + n) * 32 + mseg * 8]);
#pragma unroll
      for (int j = 0; j < 8; ++j) {
        int m = mseg * 8 + j;
        kpart[j] += b2f(p8[j]);
        int byte = (m * 128 + ptok * 2) ^ ((m & 7) << 4);
        *reinterpret_cast<unsigned short*>(((char*)phit) + byte) = p8[j];
      }
    }
    // stage x -> xst[c][t] bf16 swizzled
    {
#pragma unroll
      for (int tt = 0; tt < 8; ++tt) {
        int t = tgrp * 8 + tt;
        f32x4 v4 = *reinterpret_cast<const f32x4*>(
            x + (size_t)(b * 4096 + t0 + t) * 128 + cgrp * 4);
#pragma unroll
        for (int i = 0; i < 4; ++i) {
          int c = cgrp * 4 + i;
          int byte = (c * 128 + t * 2) ^ ((c & 7) << 4);
          *reinterpret_cast<unsigned short*>(((char*)xst) + byte) = f2b(v4[i]);
        }
      }
    }
    __syncthreads();
    // MFMA: wave w owns c-cols 32w..32w+31; D[m][c]
#pragma unroll
    for (int ks = 0; ks < 2; ++ks) {
      int byteA0 = (li * 128 + (ks * 32 + g * 8) * 2) ^ ((li & 7) << 4);
      int byteA1 = ((16 + li) * 128 + (ks * 32 + g * 8) * 2) ^ ((li & 7) << 4);
      short8 a0 = *reinterpret_cast<const short8*>(((const char*)phit) + byteA0);
      short8 a1 = *reinterpret_cast<const short8*>(((const char*)phit) + byteA1);
#pragma unroll
      for (int fc = 0; fc < 2; ++fc) {
        int c = w * 32 + fc * 16 + li;
        int byteB = (c * 128 + (ks * 32 + g * 8) * 2) ^ ((c & 7) << 4);
        short8 bb = *reinterpret_cast<const short8*>(((const char*)xst) + byteB);
        acc[0][fc] = __builtin_amdgcn_mfma_f32_16x16x32_bf16(a0, bb, acc[0][fc], 0, 0, 0);
        acc[1][fc] = __builtin_amdgcn_mfma_f32_16x16x32_bf16(a1, bb, acc[1][fc], 0, 0, 0);
      }
    }
  }
#pragma unroll
  for (int fm = 0; fm < 2; ++fm)
#pragma unroll
    for (int fc = 0; fc < 2; ++fc)
#pragma unroll
      for (int r = 0; r < 4; ++r) {
        int m = fm * 16 + g * 4 + r;
        int c = w * 32 + fc * 16 + li;
        atomicAdd(&S[(size_t)bh * 4096 + m * 128 + c], acc[fm][fc][r]);
      }
#pragma unroll
  for (int j = 0; j < 8; ++j) atomicAdd(&ksums[mseg * 8 + j], kpart[j]);
  __syncthreads();
  if (tid < 32) atomicAdd(&ksum[bh * 32 + tid], ksums[tid]);
}

// ---------------- K3: kvs = S@Wv^T + ksum*bv; Gt = kvs@Wo^T ----------------
__global__ __launch_bounds__(256) void k_fold(
    const float* __restrict__ S, const float* __restrict__ wv,
    const float* __restrict__ bv, const float* __restrict__ wo,
    const float* __restrict__ ksum, unsigned short* __restrict__ Gt) {
  __shared__ float ss[32 * 128];   // 16KB
  __shared__ float wvs[64 * 128];  // 32KB [d][c]
  __shared__ float kvl[32 * 64];   // 8KB [m][d]
  __shared__ float wos[64 * 64];   // 16KB [d][c']
  __shared__ float bvs[64];
  __shared__ float kss[32];
  int tid = threadIdx.x;
  int bh = blockIdx.x, h = bh & 7;
  for (int i = tid; i < 4096; i += 256) ss[i] = S[(size_t)bh * 4096 + i];
  for (int i = tid; i < 8192; i += 256) wvs[i] = wv[(size_t)h * 8192 + i];
  {
    int c = tid >> 2, dseg = tid & 3;
#pragma unroll
    for (int jj = 0; jj < 16; ++jj) {
      int d = dseg * 16 + jj;
      wos[d * 64 + c] = wo[c * 512 + h * 64 + d];
    }
  }
  if (tid < 64) bvs[tid] = bv[h * 64 + tid];
  if (tid < 32) kss[tid] = ksum[bh * 32 + tid];
  __syncthreads();
  {
    int m = tid >> 3, dg = tid & 7;
#pragma unroll
    for (int i = 0; i < 8; ++i) {
      int d = dg * 8 + i;
      float a = kss[m] * bvs[d];
      for (int c = 0; c < 128; ++c) a += ss[m * 128 + c] * wvs[d * 128 + c];
      kvl[m * 64 + d] = a;
    }
  }
  __syncthreads();
  int cp = tid & 63, mseg = tid >> 6;
  us8 outv;
#pragma unroll
  for (int jj = 0; jj < 8; ++jj) {
    int m = mseg * 8 + jj;
    float a = 0.f;
    for (int d = 0; d < 64; ++d) a += kvl[m * 64 + d] * wos[d * 64 + cp];
    outv[jj] = f2b(a);
  }
  *reinterpret_cast<us8*>(Gt + ((size_t)bh * 64 + cp) * 32 + mseg * 8) = outv;
}

// ---------------- K4: out = sum_h (phi_q @ G_h^T)/den_h + bias (f32) ----------------
__global__ __launch_bounds__(256) void k_out(
    const unsigned short* __restrict__ phiq, const unsigned short* __restrict__ Gt,
    const float* __restrict__ ksum, const float* __restrict__ wob,
    float* __restrict__ out) {
  int tid = threadIdx.x;
  int w = tid >> 6, l = tid & 63, g = l >> 4, li = l & 15;
  int n0 = blockIdx.x * 64 + w * 16;
  int b = (blockIdx.x * 64) >> 12;
  const short* phi_s = reinterpret_cast<const short*>(phiq);
  const short* gt_s = reinterpret_cast<const short*>(Gt);
  f32x4 oacc[4] = {};
#pragma unroll
  for (int h = 0; h < 8; ++h) {
    int bh = b * 8 + h;
    int tok = n0 + li;
    short8 a = *reinterpret_cast<const short8*>(phi_s + ((size_t)h * 65536 + tok) * 32 + g * 8);
    const float* ksrow = ksum + bh * 32 + g * 8;
    float den = 0.f;
#pragma unroll
    for (int jj = 0; jj < 8; ++jj) den += b2f((unsigned short)a[jj]) * ksrow[jj];
    den += __shfl_xor(den, 16, 64);
    den += __shfl_xor(den, 32, 64);
    float rd = 1.0f / den;
    f32x4 nm[4];
#pragma unroll
    for (int fj = 0; fj < 4; ++fj) {
      short8 bb = *reinterpret_cast<const short8*>(gt_s + ((size_t)bh * 64 + fj * 16 + li) * 32 + g * 8);
      f32x4 z = {};
      nm[fj] = __builtin_amdgcn_mfma_f32_16x16x32_bf16(a, bb, z, 0, 0, 0);
    }
#pragma unroll
    for (int r = 0; r < 4; ++r) {
      float rdr = __shfl(rd, g * 4 + r, 64);
#pragma unroll
      for (int fj = 0; fj < 4; ++fj) oacc[fj][r] += nm[fj][r] * rdr;
    }
  }
#pragma unroll
  for (int fj = 0; fj < 4; ++fj) {
    float bias = wob[fj * 16 + li];
#pragma unroll
    for (int r = 0; r < 4; ++r) {
      int n = n0 + g * 4 + r;
      out[(size_t)n * 64 + fj * 16 + li] = oacc[fj][r] + bias;
    }
  }
}

extern "C" void kernel_launch(void* const* d_in, const int* in_sizes, int n_in,
                              void* d_out, int out_size, void* d_ws, size_t ws_size,
                              hipStream_t stream) {
  const int expect[10] = {8388608, 65536, 512, 65536, 512, 65536, 512, 32768, 64, 1920};
  if (n_in != 10) return;
  for (int i = 0; i < 10; ++i) if (in_sizes[i] != expect[i]) return;
  if (out_size != 4194304) return;
  if (ws_size < WS_NEED) return;

  const float* x    = (const float*)d_in[0];
  const float* wq   = (const float*)d_in[1];
  const float* bq   = (const float*)d_in[2];
  const float* wk   = (const float*)d_in[3];
  const float* bk   = (const float*)d_in[4];
  const float* wv   = (const float*)d_in[5];
  const float* bv   = (const float*)d_in[6];
  const float* wo   = (const float*)d_in[7];
  const float* wob  = (const float*)d_in[8];
  const float* proj = (const float*)d_in[9];

  char* ws = (char*)d_ws;
  unsigned short* wqkv = (unsigned short*)(ws + OF_WQKV);
  float*          wbp  = (float*)(ws + OF_WBP);
  unsigned short* phiq = (unsigned short*)(ws + OF_PHIQ);
  unsigned short* phik = (unsigned short*)(ws + OF_PHIK);
  float*          S    = (float*)(ws + OF_S);
  float*          ksum = (float*)(ws + OF_KSUM);
  unsigned short* Gt   = (unsigned short*)(ws + OF_GT);

  // zero S + ksum (contiguous)
  (void)hipMemsetAsync(ws + OF_S, 0, 2097152 + 16384, stream);

  k_pack<<<529, 256, 0, stream>>>(wq, wk, bq, bk, proj, wqkv, wbp);
  k_qkv<<<1024, 256, 0, stream>>>(x, wqkv, wbp, phiq, phik);
  k_S<<<512, 256, 0, stream>>>(phik, x, S, ksum);
  k_fold<<<128, 256, 0, stream>>>(S, wv, bv, wo, ksum, Gt);
  k_out<<<1024, 256, 0, stream>>>(phiq, Gt, ksum, wob, (float*)d_out);
}

// Round 12
// 209.868 us; speedup vs baseline: 1.0281x; 1.0281x over previous
//
// ROUND 12: write-wall attack. (1) phiq never written: k_out fuses q-GEMM+phi
// (r11-proven blocks) -> out. (2) k_S atomic-free: per-block partial S2, summed
// in k_fold. (3) x pre-converted to bf16 once (k_xconv) - staging is us8 loads.
#include <hip/hip_runtime.h>
#include <cstdint>

typedef __attribute__((ext_vector_type(4))) float f32x4;
typedef __attribute__((ext_vector_type(8))) short short8;
typedef __attribute__((ext_vector_type(8))) unsigned short us8;

#define DEV __device__ __forceinline__

DEV unsigned short f2b(float f) {
  unsigned u = __builtin_bit_cast(unsigned, f);
  return (unsigned short)((u + 0x7fffu + ((u >> 16) & 1u)) >> 16);
}
DEV float b2f(unsigned short h) {
  unsigned u = ((unsigned)h) << 16;
  return __builtin_bit_cast(float, u);
}

constexpr float SQ_SCALE = 0.35355339059327379f;    // 64^-0.25 (tau=1)
constexpr float RATIO    = 0.18257418583505536f;    // 1/sqrt(30)
constexpr float REPS     = 0.18257418583505536e-6f; // RATIO * 1e-6

// B=16, T=4096, N=65536, C_IN=128, H=8, D=64, M=30 (pad 32)
// wqkv cols: [0,512) q | [512,1024) k | [1024,1280) ddq | [1280,1536) ddk
constexpr size_t OF_WQKV = 0;          // 1536*128 bf16 = 393216
constexpr size_t OF_WBP  = 393216;     // 1536 f32 (pad 8192)
constexpr size_t OF_XBF  = 401408;     // [65536][128] bf16 = 16777216
constexpr size_t OF_PHIK = 17178624;   // [8][65536][32] bf16 = 33554432
constexpr size_t OF_S2   = 50733056;   // [512][32][128] f32 = 8388608
constexpr size_t OF_KSUM = 59121664;   // [128][32] f32 = 16384
constexpr size_t OF_GT   = 59138048;   // [128][64][32] bf16 = 524288
constexpr size_t WS_NEED = 59662336;

// ---------------- K0: pack scaled q/k weights + fold proj ----------------
__global__ __launch_bounds__(256) void k_pack(
    const float* __restrict__ wq, const float* __restrict__ wk,
    const float* __restrict__ bq, const float* __restrict__ bk,
    const float* __restrict__ proj,
    unsigned short* __restrict__ wqkv, float* __restrict__ wbp) {
  int bid = blockIdx.x, tid = threadIdx.x;
  if (bid < 512) {
    int id = bid * 256 + tid;            // cols 0..1023 (q then k)
    int c = id >> 7, k = id & 127;
    int mat = c >> 9, row = c & 511;
    const float* w = (mat == 0) ? wq : wk;
    wqkv[id] = f2b(w[row * 128 + k] * SQ_SCALE);
  } else if (bid < 528) {
    __shared__ float wsm[64 * 128];
    __shared__ float ps[32 * 64];
    __shared__ float bs[64];
    int db = bid - 512, mat2 = db >> 3, h = db & 7;
    const float* wsrc = (mat2 == 0) ? wq : wk;
    const float* bsrc = (mat2 == 0) ? bq : bk;
    for (int i = tid; i < 8192; i += 256) wsm[i] = wsrc[h * 8192 + i] * SQ_SCALE;
    for (int i = tid; i < 2048; i += 256) {
      int m = i >> 6, d = i & 63;
      ps[i] = (m < 30) ? proj[m * 64 + d] : 0.0f;
    }
    if (tid < 64) bs[tid] = bsrc[h * 64 + tid] * SQ_SCALE;
    __syncthreads();
    int m = tid >> 3, kseg = tid & 7;
    int col = 1024 + mat2 * 256 + h * 32 + m;
#pragma unroll 4
    for (int kk = 0; kk < 16; ++kk) {
      int k = kseg * 16 + kk;
      float a = 0.f;
      for (int d = 0; d < 64; ++d) a += ps[m * 64 + d] * wsm[d * 128 + k];
      wqkv[col * 128 + k] = f2b(a);
    }
    if (tid < 32) {
      float a = 0.f;
      for (int d = 0; d < 64; ++d) a += ps[tid * 64 + d] * bs[d];
      wbp[1024 + mat2 * 256 + h * 32 + tid] = a;
    }
  } else {
    for (int i = tid; i < 1024; i += 256) {
      int mat = i >> 9, row = i & 511;
      const float* bb = (mat == 0) ? bq : bk;
      wbp[i] = bb[row] * SQ_SCALE;
    }
  }
}

// ---------------- K0b: x -> bf16 [t][c] once ----------------
__global__ __launch_bounds__(256) void k_xconv(
    const float* __restrict__ x, unsigned short* __restrict__ xbf) {
  size_t base = ((size_t)blockIdx.x * 256 + threadIdx.x) * 16;
  f32x4 a0 = *reinterpret_cast<const f32x4*>(x + base);
  f32x4 a1 = *reinterpret_cast<const f32x4*>(x + base + 4);
  f32x4 a2 = *reinterpret_cast<const f32x4*>(x + base + 8);
  f32x4 a3 = *reinterpret_cast<const f32x4*>(x + base + 12);
  us8 o0, o1;
  o0[0] = f2b(a0[0]); o0[1] = f2b(a0[1]); o0[2] = f2b(a0[2]); o0[3] = f2b(a0[3]);
  o0[4] = f2b(a1[0]); o0[5] = f2b(a1[1]); o0[6] = f2b(a1[2]); o0[7] = f2b(a1[3]);
  o1[0] = f2b(a2[0]); o1[1] = f2b(a2[1]); o1[2] = f2b(a2[2]); o1[3] = f2b(a2[3]);
  o1[4] = f2b(a3[0]); o1[5] = f2b(a3[1]); o1[6] = f2b(a3[2]); o1[7] = f2b(a3[3]);
  *reinterpret_cast<us8*>(xbf + base) = o0;
  *reinterpret_cast<us8*>(xbf + base + 8) = o1;
}

// shared helper: stage 64x128 bf16 x-tile (swizzled) from xbf
DEV void stage_x(const unsigned short* xbf, unsigned short* xs, int n0, int tid) {
  int row = tid >> 2, seg = tid & 3;
  const unsigned short* src = xbf + (size_t)(n0 + row) * 128 + seg * 32;
#pragma unroll
  for (int q8 = 0; q8 < 4; ++q8) {
    us8 o = *reinterpret_cast<const us8*>(src + q8 * 8);
    int byte = (row * 256 + seg * 64 + q8 * 16) ^ ((row & 7) << 4);
    *reinterpret_cast<us8*>(((char*)xs) + byte) = o;
  }
}

// ---------------- K1: k-side GEMM -> diag_k, phi_k ----------------
__global__ __launch_bounds__(256) void k_qkv(
    const unsigned short* __restrict__ xbf, const unsigned short* __restrict__ wqkv,
    const float* __restrict__ wbp, unsigned short* __restrict__ phik) {
  __shared__ unsigned short xs[64 * 128];      // 16KB
  __shared__ unsigned short scratch[4][2048];  // 16KB (4KB/wave)
  __shared__ float diag_s[512];                // [h*64 + tok]

  int tid = threadIdx.x;
  int w = tid >> 6, l = tid & 63;
  int g = l >> 4, li = l & 15;
  int n0 = blockIdx.x * 64;

  stage_x(xbf, xs, n0, tid);
  __syncthreads();

  const short* wq_s = reinterpret_cast<const short*>(wqkv);
  char* scr = (char*)scratch[w];

  for (int j = 0; j < 3; ++j) {
    if (j == 2) __syncthreads();   // diag complete before ddk
    int bcol = (j < 2) ? (512 + j * 256 + w * 64) : (1280 + w * 64);

    f32x4 acc[4][4] = {};
#pragma unroll
    for (int ks = 0; ks < 4; ++ks) {
      short8 a[4], bb[4];
#pragma unroll
      for (int fi = 0; fi < 4; ++fi) {
        int tokl = fi * 16 + li;
        int byte = (tokl * 256 + (ks * 32 + g * 8) * 2) ^ ((tokl & 7) << 4);
        a[fi] = *reinterpret_cast<const short8*>(((const char*)xs) + byte);
      }
#pragma unroll
      for (int fj = 0; fj < 4; ++fj)
        bb[fj] = *reinterpret_cast<const short8*>(wq_s + (bcol + fj * 16 + li) * 128 + ks * 32 + g * 8);
#pragma unroll
      for (int fi = 0; fi < 4; ++fi)
#pragma unroll
        for (int fj = 0; fj < 4; ++fj)
          acc[fi][fj] = __builtin_amdgcn_mfma_f32_16x16x32_bf16(a[fi], bb[fj], acc[fi][fj], 0, 0, 0);
    }
#pragma unroll
    for (int fj = 0; fj < 4; ++fj) {
      float bias = wbp[bcol + fj * 16 + li];
#pragma unroll
      for (int fi = 0; fi < 4; ++fi)
#pragma unroll
        for (int r = 0; r < 4; ++r) acc[fi][fj][r] += bias;
    }

    if (j < 2) {
      int h = j * 4 + w;
      float t4[4][4];
#pragma unroll
      for (int fi = 0; fi < 4; ++fi)
#pragma unroll
        for (int r = 0; r < 4; ++r) {
          float s = 0.f;
#pragma unroll
          for (int fj = 0; fj < 4; ++fj) { float v = acc[fi][fj][r]; s += v * v; }
          t4[fi][r] = s;
        }
#pragma unroll
      for (int mask = 1; mask <= 8; mask <<= 1)
#pragma unroll
        for (int fi = 0; fi < 4; ++fi)
#pragma unroll
          for (int r = 0; r < 4; ++r)
            t4[fi][r] += __shfl_xor(t4[fi][r], mask, 64);
      if (li == 0) {
#pragma unroll
        for (int fi = 0; fi < 4; ++fi)
#pragma unroll
          for (int r = 0; r < 4; ++r)
            diag_s[h * 64 + fi * 16 + g * 4 + r] = 0.5f * t4[fi][r];
      }
    } else {
      // ddk -> phi_k for heads 2w, 2w+1
#pragma unroll
      for (int hp = 0; hp < 2; ++hp) {
        int h = w * 2 + hp;
#pragma unroll
        for (int fj2 = 0; fj2 < 2; ++fj2) {
          int m = fj2 * 16 + li;
          bool valid = (m < 30);
#pragma unroll
          for (int fi = 0; fi < 4; ++fi)
#pragma unroll
            for (int r = 0; r < 4; ++r) {
              int tok = fi * 16 + g * 4 + r;
              float ph = valid
                  ? (RATIO * __expf(acc[fi][hp * 2 + fj2][r] - diag_s[h * 64 + tok]) + REPS)
                  : 0.0f;
              int byte = (tok * 64 + m * 2) ^ ((tok & 7) << 4);
              *reinterpret_cast<unsigned short*>(scr + byte) = f2b(ph);
            }
        }
        size_t gbase = ((size_t)h * 65536 + n0 + l) * 32;
#pragma unroll
        for (int i = 0; i < 4; ++i) {
          int byte = (l * 64 + i * 16) ^ ((l & 7) << 4);
          us8 o = *reinterpret_cast<const us8*>(scr + byte);
          *reinterpret_cast<us8*>(&phik[gbase + i * 8]) = o;
        }
      }
    }
  }
}

// ---------------- K2: partial S2[bid][m][c] = phi_k^T @ x (no atomics) ----------------
__global__ __launch_bounds__(256) void k_S(
    const unsigned short* __restrict__ phik, const unsigned short* __restrict__ xbf,
    float* __restrict__ S2, float* __restrict__ ksum) {
  __shared__ unsigned short phit[32 * 64];  // [m][tok] swizzled
  __shared__ unsigned short xst[128 * 64];  // [c][tok] swizzled
  __shared__ float ksums[32];

  int tid = threadIdx.x;
  int w = tid >> 6, l = tid & 63, g = l >> 4, li = l & 15;
  int bid = blockIdx.x;
  int bh = bid >> 2, chunk = bid & 3;
  int b = bh >> 3, h = bh & 7;
  if (tid < 32) ksums[tid] = 0.f;

  int ptok = tid & 63;
  int mseg = tid >> 6;
  int tgrp = tid >> 4, cseg = tid & 15;   // x staging: tok=tgrp(16 rows of 4), c=cseg*8
  float kpart[8] = {0, 0, 0, 0, 0, 0, 0, 0};
  f32x4 acc[2][2] = {};
  int tok0 = chunk * 1024;

  for (int tile = 0; tile < 16; ++tile) {
    int t0 = tok0 + tile * 64;
    __syncthreads();
    {
      int n = b * 4096 + t0 + ptok;
      us8 p8 = *reinterpret_cast<const us8*>(&phik[((size_t)h * 65536 + n) * 32 + mseg * 8]);
#pragma unroll
      for (int j = 0; j < 8; ++j) {
        int m = mseg * 8 + j;
        kpart[j] += b2f(p8[j]);
        int byte = (m * 128 + ptok * 2) ^ ((m & 7) << 4);
        *reinterpret_cast<unsigned short*>(((char*)phit) + byte) = p8[j];
      }
    }
    // stage xbf -> xst[c][t]: thread covers 4 tokens x 8 c
    {
#pragma unroll
      for (int tt = 0; tt < 4; ++tt) {
        int t = tgrp * 4 + tt;
        us8 v8 = *reinterpret_cast<const us8*>(
            xbf + (size_t)(b * 4096 + t0 + t) * 128 + cseg * 8);
#pragma unroll
        for (int i = 0; i < 8; ++i) {
          int c = cseg * 8 + i;
          int byte = (c * 128 + t * 2) ^ ((c & 7) << 4);
          *reinterpret_cast<unsigned short*>(((char*)xst) + byte) = v8[i];
        }
      }
    }
    __syncthreads();
#pragma unroll
    for (int ks = 0; ks < 2; ++ks) {
      int byteA0 = (li * 128 + (ks * 32 + g * 8) * 2) ^ ((li & 7) << 4);
      int byteA1 = ((16 + li) * 128 + (ks * 32 + g * 8) * 2) ^ ((li & 7) << 4);
      short8 a0 = *reinterpret_cast<const short8*>(((const char*)phit) + byteA0);
      short8 a1 = *reinterpret_cast<const short8*>(((const char*)phit) + byteA1);
#pragma unroll
      for (int fc = 0; fc < 2; ++fc) {
        int c = w * 32 + fc * 16 + li;
        int byteB = (c * 128 + (ks * 32 + g * 8) * 2) ^ ((c & 7) << 4);
        short8 bb = *reinterpret_cast<const short8*>(((const char*)xst) + byteB);
        acc[0][fc] = __builtin_amdgcn_mfma_f32_16x16x32_bf16(a0, bb, acc[0][fc], 0, 0, 0);
        acc[1][fc] = __builtin_amdgcn_mfma_f32_16x16x32_bf16(a1, bb, acc[1][fc], 0, 0, 0);
      }
    }
  }
  // direct store of this block's partial (no atomics)
#pragma unroll
  for (int fm = 0; fm < 2; ++fm)
#pragma unroll
    for (int fc = 0; fc < 2; ++fc)
#pragma unroll
      for (int r = 0; r < 4; ++r) {
        int m = fm * 16 + g * 4 + r;
        int c = w * 32 + fc * 16 + li;
        S2[(size_t)bid * 4096 + m * 128 + c] = acc[fm][fc][r];
      }
#pragma unroll
  for (int j = 0; j < 8; ++j) atomicAdd(&ksums[mseg * 8 + j], kpart[j]);
  __syncthreads();
  if (tid < 32) atomicAdd(&ksum[bh * 32 + tid], ksums[tid]);
}

// ---------------- K3: sum partials; kvs = S@Wv^T + ksum*bv; Gt = kvs@Wo^T ----------------
__global__ __launch_bounds__(256) void k_fold(
    const float* __restrict__ S2, const float* __restrict__ wv,
    const float* __restrict__ bv, const float* __restrict__ wo,
    const float* __restrict__ ksum, unsigned short* __restrict__ Gt) {
  __shared__ float ss[32 * 128];
  __shared__ float wvs[64 * 128];  // [d][c]
  __shared__ float kvl[32 * 64];   // [m][d]
  __shared__ float wos[64 * 64];   // [d][c']
  __shared__ float bvs[64];
  __shared__ float kss[32];
  int tid = threadIdx.x;
  int bh = blockIdx.x, h = bh & 7;
  for (int i = tid; i < 4096; i += 256) {
    float a = 0.f;
#pragma unroll
    for (int c = 0; c < 4; ++c) a += S2[(size_t)(bh * 4 + c) * 4096 + i];
    ss[i] = a;
  }
  for (int i = tid; i < 8192; i += 256) wvs[i] = wv[(size_t)h * 8192 + i];
  {
    int c = tid >> 2, dseg = tid & 3;
#pragma unroll
    for (int jj = 0; jj < 16; ++jj) {
      int d = dseg * 16 + jj;
      wos[d * 64 + c] = wo[c * 512 + h * 64 + d];
    }
  }
  if (tid < 64) bvs[tid] = bv[h * 64 + tid];
  if (tid < 32) kss[tid] = ksum[bh * 32 + tid];
  __syncthreads();
  {
    int m = tid >> 3, dg = tid & 7;
#pragma unroll
    for (int i = 0; i < 8; ++i) {
      int d = dg * 8 + i;
      float a = kss[m] * bvs[d];
      for (int c = 0; c < 128; ++c) a += ss[m * 128 + c] * wvs[d * 128 + c];
      kvl[m * 64 + d] = a;
    }
  }
  __syncthreads();
  int cp = tid & 63, mseg = tid >> 6;
  us8 outv;
#pragma unroll
  for (int jj = 0; jj < 8; ++jj) {
    int m = mseg * 8 + jj;
    float a = 0.f;
    for (int d = 0; d < 64; ++d) a += kvl[m * 64 + d] * wos[d * 64 + cp];
    outv[jj] = f2b(a);
  }
  *reinterpret_cast<us8*>(Gt + ((size_t)bh * 64 + cp) * 32 + mseg * 8) = outv;
}

// ---------------- K4: fused q-GEMM + phi_q + out ----------------
__global__ __launch_bounds__(256) void k_out(
    const unsigned short* __restrict__ xbf, const unsigned short* __restrict__ wqkv,
    const float* __restrict__ wbp, const unsigned short* __restrict__ Gt,
    const float* __restrict__ ksum, const float* __restrict__ wob,
    float* __restrict__ out) {
  __shared__ unsigned short xs[64 * 128];   // 16KB
  __shared__ unsigned short phiqs[8 * 2048];// 32KB: [h][64 tok][32 m] swizzled
  __shared__ float diag_s[512];             // [h*64 + tok]

  int tid = threadIdx.x;
  int w = tid >> 6, l = tid & 63;
  int g = l >> 4, li = l & 15;
  int n0 = blockIdx.x * 64;
  int b = n0 >> 12;

  stage_x(xbf, xs, n0, tid);
  __syncthreads();

  const short* wq_s = reinterpret_cast<const short*>(wqkv);

  // ---- phase 1: q-GEMM + diag + phi_q -> LDS ----
  for (int j = 0; j < 3; ++j) {
    if (j == 2) __syncthreads();   // diag complete before ddq
    int bcol = (j < 2) ? (j * 256 + w * 64) : (1024 + w * 64);

    f32x4 acc[4][4] = {};
#pragma unroll
    for (int ks = 0; ks < 4; ++ks) {
      short8 a[4], bb[4];
#pragma unroll
      for (int fi = 0; fi < 4; ++fi) {
        int tokl = fi * 16 + li;
        int byte = (tokl * 256 + (ks * 32 + g * 8) * 2) ^ ((tokl & 7) << 4);
        a[fi] = *reinterpret_cast<const short8*>(((const char*)xs) + byte);
      }
#pragma unroll
      for (int fj = 0; fj < 4; ++fj)
        bb[fj] = *reinterpret_cast<const short8*>(wq_s + (bcol + fj * 16 + li) * 128 + ks * 32 + g * 8);
#pragma unroll
      for (int fi = 0; fi < 4; ++fi)
#pragma unroll
        for (int fj = 0; fj < 4; ++fj)
          acc[fi][fj] = __builtin_amdgcn_mfma_f32_16x16x32_bf16(a[fi], bb[fj], acc[fi][fj], 0, 0, 0);
    }
#pragma unroll
    for (int fj = 0; fj < 4; ++fj) {
      float bias = wbp[bcol + fj * 16 + li];
#pragma unroll
      for (int fi = 0; fi < 4; ++fi)
#pragma unroll
        for (int r = 0; r < 4; ++r) acc[fi][fj][r] += bias;
    }

    if (j < 2) {
      int h = j * 4 + w;
      float t4[4][4];
#pragma unroll
      for (int fi = 0; fi < 4; ++fi)
#pragma unroll
        for (int r = 0; r < 4; ++r) {
          float s = 0.f;
#pragma unroll
          for (int fj = 0; fj < 4; ++fj) { float v = acc[fi][fj][r]; s += v * v; }
          t4[fi][r] = s;
        }
#pragma unroll
      for (int mask = 1; mask <= 8; mask <<= 1)
#pragma unroll
        for (int fi = 0; fi < 4; ++fi)
#pragma unroll
          for (int r = 0; r < 4; ++r)
            t4[fi][r] += __shfl_xor(t4[fi][r], mask, 64);
      if (li == 0) {
#pragma unroll
        for (int fi = 0; fi < 4; ++fi)
#pragma unroll
          for (int r = 0; r < 4; ++r)
            diag_s[h * 64 + fi * 16 + g * 4 + r] = 0.5f * t4[fi][r];
      }
    } else {
      // ddq -> phi_q for heads 2w, 2w+1 into phiqs
#pragma unroll
      for (int hp = 0; hp < 2; ++hp) {
        int h = w * 2 + hp;
        char* st = ((char*)phiqs) + h * 4096;
#pragma unroll
        for (int fj2 = 0; fj2 < 2; ++fj2) {
          int m = fj2 * 16 + li;
          bool valid = (m < 30);
#pragma unroll
          for (int fi = 0; fi < 4; ++fi)
#pragma unroll
            for (int r = 0; r < 4; ++r) {
              int tok = fi * 16 + g * 4 + r;
              float ph = valid
                  ? (RATIO * __expf(acc[fi][hp * 2 + fj2][r] - diag_s[h * 64 + tok]) + REPS)
                  : 0.0f;
              int byte = (tok * 64 + m * 2) ^ ((tok & 7) << 4);
              *reinterpret_cast<unsigned short*>(st + byte) = f2b(ph);
            }
        }
      }
    }
  }
  __syncthreads();   // phiqs complete

  // ---- phase 2: out = sum_h (phi_q @ G_h^T)/den_h + bias ----
  const short* gt_s = reinterpret_cast<const short*>(Gt);
  int tokl = w * 16 + li;
  f32x4 oacc[4] = {};
#pragma unroll
  for (int h = 0; h < 8; ++h) {
    int bh = b * 8 + h;
    int abyte = h * 4096 + ((tokl * 64 + g * 16) ^ ((tokl & 7) << 4));
    short8 a = *reinterpret_cast<const short8*>(((const char*)phiqs) + abyte);
    const float* ksrow = ksum + bh * 32 + g * 8;
    float den = 0.f;
#pragma unroll
    for (int jj = 0; jj < 8; ++jj) den += b2f((unsigned short)a[jj]) * ksrow[jj];
    den += __shfl_xor(den, 16, 64);
    den += __shfl_xor(den, 32, 64);
    float rd = 1.0f / den;
    f32x4 nm[4];
#pragma unroll
    for (int fj = 0; fj < 4; ++fj) {
      short8 bb = *reinterpret_cast<const short8*>(gt_s + ((size_t)bh * 64 + fj * 16 + li) * 32 + g * 8);
      f32x4 z = {};
      nm[fj] = __builtin_amdgcn_mfma_f32_16x16x32_bf16(a, bb, z, 0, 0, 0);
    }
#pragma unroll
    for (int r = 0; r < 4; ++r) {
      float rdr = __shfl(rd, g * 4 + r, 64);
#pragma unroll
      for (int fj = 0; fj < 4; ++fj) oacc[fj][r] += nm[fj][r] * rdr;
    }
  }
#pragma unroll
  for (int fj = 0; fj < 4; ++fj) {
    float bias = wob[fj * 16 + li];
#pragma unroll
    for (int r = 0; r < 4; ++r) {
      int n = n0 + w * 16 + g * 4 + r;
      out[(size_t)n * 64 + fj * 16 + li] = oacc[fj][r] + bias;
    }
  }
}

extern "C" void kernel_launch(void* const* d_in, const int* in_sizes, int n_in,
                              void* d_out, int out_size, void* d_ws, size_t ws_size,
                              hipStream_t stream) {
  const int expect[10] = {8388608, 65536, 512, 65536, 512, 65536, 512, 32768, 64, 1920};
  if (n_in != 10) return;
  for (int i = 0; i < 10; ++i) if (in_sizes[i] != expect[i]) return;
  if (out_size != 4194304) return;
  if (ws_size < WS_NEED) return;

  const float* x    = (const float*)d_in[0];
  const float* wq   = (const float*)d_in[1];
  const float* bq   = (const float*)d_in[2];
  const float* wk   = (const float*)d_in[3];
  const float* bk   = (const float*)d_in[4];
  const float* wv   = (const float*)d_in[5];
  const float* bv   = (const float*)d_in[6];
  const float* wo   = (const float*)d_in[7];
  const float* wob  = (const float*)d_in[8];
  const float* proj = (const float*)d_in[9];

  char* ws = (char*)d_ws;
  unsigned short* wqkv = (unsigned short*)(ws + OF_WQKV);
  float*          wbp  = (float*)(ws + OF_WBP);
  unsigned short* xbf  = (unsigned short*)(ws + OF_XBF);
  unsigned short* phik = (unsigned short*)(ws + OF_PHIK);
  float*          S2   = (float*)(ws + OF_S2);
  float*          ksum = (float*)(ws + OF_KSUM);
  unsigned short* Gt   = (unsigned short*)(ws + OF_GT);

  (void)hipMemsetAsync(ws + OF_KSUM, 0, 16384, stream);

  k_pack<<<529, 256, 0, stream>>>(wq, wk, bq, bk, proj, wqkv, wbp);
  k_xconv<<<2048, 256, 0, stream>>>(x, xbf);
  k_qkv<<<1024, 256, 0, stream>>>(xbf, wqkv, wbp, phik);
  k_S<<<512, 256, 0, stream>>>(phik, xbf, S2, ksum);
  k_fold<<<128, 256, 0, stream>>>(S2, wv, bv, wo, ksum, Gt);
  k_out<<<1024, 256, 0, stream>>>(xbf, wqkv, wbp, Gt, ksum, wob, (float*)d_out);
}

// Round 13
// 180.443 us; speedup vs baseline: 1.1957x; 1.1631x over previous
//
// ROUND 13: LDS-free k_S. Producers emit t-major layouts (phikT[h*32+m][n],
// xbfT[c][n]); k_S loads MFMA fragments straight from global (no LDS, no
// barriers), killing the 31M bank conflicts that were 51us of its 76us.
#include <hip/hip_runtime.h>
#include <cstdint>

typedef __attribute__((ext_vector_type(4))) float f32x4;
typedef __attribute__((ext_vector_type(8))) short short8;
typedef __attribute__((ext_vector_type(8))) unsigned short us8;

#define DEV __device__ __forceinline__

DEV unsigned short f2b(float f) {
  unsigned u = __builtin_bit_cast(unsigned, f);
  return (unsigned short)((u + 0x7fffu + ((u >> 16) & 1u)) >> 16);
}
DEV float b2f(unsigned short h) {
  unsigned u = ((unsigned)h) << 16;
  return __builtin_bit_cast(float, u);
}

constexpr float SQ_SCALE = 0.35355339059327379f;    // 64^-0.25 (tau=1)
constexpr float RATIO    = 0.18257418583505536f;    // 1/sqrt(30)
constexpr float REPS     = 0.18257418583505536e-6f; // RATIO * 1e-6

// B=16, T=4096, N=65536, C_IN=128, H=8, D=64, M=30 (pad 32)
// wqkv cols: [0,512) q | [512,1024) k | [1024,1280) ddq | [1280,1536) ddk
constexpr size_t OF_WQKV  = 0;          // 1536*128 bf16 = 393216
constexpr size_t OF_WBP   = 393216;     // 1536 f32 (pad 8192)
constexpr size_t OF_XBF   = 401408;     // [65536][128] bf16 = 16777216
constexpr size_t OF_XBFT  = 17178624;   // [128][65536] bf16 = 16777216
constexpr size_t OF_PHIKT = 33955840;   // [256][65536] bf16 = 33554432 ([h*32+m][n])
constexpr size_t OF_S2    = 67510272;   // [1024][32][128] f32 = 16777216
constexpr size_t OF_KSUM  = 84287488;   // [128][32] f32 = 16384
constexpr size_t OF_GT    = 84303872;   // [128][64][32] bf16 = 524288
constexpr size_t WS_NEED  = 84828160;

// ---------------- K0: pack scaled q/k weights + fold proj ----------------
__global__ __launch_bounds__(256) void k_pack(
    const float* __restrict__ wq, const float* __restrict__ wk,
    const float* __restrict__ bq, const float* __restrict__ bk,
    const float* __restrict__ proj,
    unsigned short* __restrict__ wqkv, float* __restrict__ wbp) {
  int bid = blockIdx.x, tid = threadIdx.x;
  if (bid < 512) {
    int id = bid * 256 + tid;            // cols 0..1023 (q then k)
    int c = id >> 7, k = id & 127;
    int mat = c >> 9, row = c & 511;
    const float* w = (mat == 0) ? wq : wk;
    wqkv[id] = f2b(w[row * 128 + k] * SQ_SCALE);
  } else if (bid < 528) {
    __shared__ float wsm[64 * 128];
    __shared__ float ps[32 * 64];
    __shared__ float bs[64];
    int db = bid - 512, mat2 = db >> 3, h = db & 7;
    const float* wsrc = (mat2 == 0) ? wq : wk;
    const float* bsrc = (mat2 == 0) ? bq : bk;
    for (int i = tid; i < 8192; i += 256) wsm[i] = wsrc[h * 8192 + i] * SQ_SCALE;
    for (int i = tid; i < 2048; i += 256) {
      int m = i >> 6, d = i & 63;
      ps[i] = (m < 30) ? proj[m * 64 + d] : 0.0f;
    }
    if (tid < 64) bs[tid] = bsrc[h * 64 + tid] * SQ_SCALE;
    __syncthreads();
    int m = tid >> 3, kseg = tid & 7;
    int col = 1024 + mat2 * 256 + h * 32 + m;
#pragma unroll 4
    for (int kk = 0; kk < 16; ++kk) {
      int k = kseg * 16 + kk;
      float a = 0.f;
      for (int d = 0; d < 64; ++d) a += ps[m * 64 + d] * wsm[d * 128 + k];
      wqkv[col * 128 + k] = f2b(a);
    }
    if (tid < 32) {
      float a = 0.f;
      for (int d = 0; d < 64; ++d) a += ps[tid * 64 + d] * bs[d];
      wbp[1024 + mat2 * 256 + h * 32 + tid] = a;
    }
  } else {
    for (int i = tid; i < 1024; i += 256) {
      int mat = i >> 9, row = i & 511;
      const float* bb = (mat == 0) ? bq : bk;
      wbp[i] = bb[row] * SQ_SCALE;
    }
  }
}

// ---------------- K0b: x -> bf16, row-major AND transposed ----------------
__global__ __launch_bounds__(256) void k_xconv(
    const float* __restrict__ x, unsigned short* __restrict__ xbf,
    unsigned short* __restrict__ xbfT) {
  __shared__ unsigned short xt[128 * 72];   // [c] rows of 144B (64 tok + pad)
  int tid = threadIdx.x;
  int n0 = blockIdx.x * 64;
  int tok = tid & 63, cgrp = tid >> 6;      // wave-uniform cgrp
  const float* src = x + (size_t)(n0 + tok) * 128 + cgrp * 32;
  unsigned short* dst = xbf + (size_t)(n0 + tok) * 128 + cgrp * 32;
#pragma unroll
  for (int q8 = 0; q8 < 4; ++q8) {
    f32x4 a = *reinterpret_cast<const f32x4*>(src + q8 * 8);
    f32x4 c4 = *reinterpret_cast<const f32x4*>(src + q8 * 8 + 4);
    us8 o;
    o[0] = f2b(a[0]); o[1] = f2b(a[1]); o[2] = f2b(a[2]); o[3] = f2b(a[3]);
    o[4] = f2b(c4[0]); o[5] = f2b(c4[1]); o[6] = f2b(c4[2]); o[7] = f2b(c4[3]);
    *reinterpret_cast<us8*>(dst + q8 * 8) = o;
#pragma unroll
    for (int e = 0; e < 8; ++e) {
      int c = cgrp * 32 + q8 * 8 + e;       // c wave-uniform per e -> bank-free
      *reinterpret_cast<unsigned short*>(((char*)xt) + c * 144 + tok * 2) = o[e];
    }
  }
  __syncthreads();
  int c2 = tid >> 1, half = tid & 1;
#pragma unroll
  for (int i = 0; i < 4; ++i) {
    us8 o = *reinterpret_cast<const us8*>(((const char*)xt) + c2 * 144 + half * 64 + i * 16);
    *reinterpret_cast<us8*>(xbfT + (size_t)c2 * 65536 + n0 + half * 32 + i * 8) = o;
  }
}

// ---------------- K1: k-side GEMM -> diag_k, phi_k transposed ----------------
__global__ __launch_bounds__(256) void k_qkv(
    const unsigned short* __restrict__ xbf, const unsigned short* __restrict__ wqkv,
    const float* __restrict__ wbp, unsigned short* __restrict__ phikT) {
  __shared__ unsigned short xs[64 * 128];      // 16KB swizzled x-tile
  __shared__ unsigned short scratch[4][2304];  // 4.5KB/wave: 32 rows x 144B
  __shared__ float diag_s[512];                // [h*64 + tok]

  int tid = threadIdx.x;
  int w = tid >> 6, l = tid & 63;
  int g = l >> 4, li = l & 15;
  int n0 = blockIdx.x * 64;

  {
    int row = tid >> 2, seg = tid & 3;
    const unsigned short* src = xbf + (size_t)(n0 + row) * 128 + seg * 32;
#pragma unroll
    for (int q8 = 0; q8 < 4; ++q8) {
      us8 o = *reinterpret_cast<const us8*>(src + q8 * 8);
      int byte = (row * 256 + seg * 64 + q8 * 16) ^ ((row & 7) << 4);
      *reinterpret_cast<us8*>(((char*)xs) + byte) = o;
    }
  }
  __syncthreads();

  const short* wq_s = reinterpret_cast<const short*>(wqkv);
  char* scr = (char*)scratch[w];

  for (int j = 0; j < 3; ++j) {
    if (j == 2) __syncthreads();   // diag complete before ddk
    int bcol = (j < 2) ? (512 + j * 256 + w * 64) : (1280 + w * 64);

    f32x4 acc[4][4] = {};
#pragma unroll
    for (int ks = 0; ks < 4; ++ks) {
      short8 a[4], bb[4];
#pragma unroll
      for (int fi = 0; fi < 4; ++fi) {
        int tokl = fi * 16 + li;
        int byte = (tokl * 256 + (ks * 32 + g * 8) * 2) ^ ((tokl & 7) << 4);
        a[fi] = *reinterpret_cast<const short8*>(((const char*)xs) + byte);
      }
#pragma unroll
      for (int fj = 0; fj < 4; ++fj)
        bb[fj] = *reinterpret_cast<const short8*>(wq_s + (bcol + fj * 16 + li) * 128 + ks * 32 + g * 8);
#pragma unroll
      for (int fi = 0; fi < 4; ++fi)
#pragma unroll
        for (int fj = 0; fj < 4; ++fj)
          acc[fi][fj] = __builtin_amdgcn_mfma_f32_16x16x32_bf16(a[fi], bb[fj], acc[fi][fj], 0, 0, 0);
    }
#pragma unroll
    for (int fj = 0; fj < 4; ++fj) {
      float bias = wbp[bcol + fj * 16 + li];
#pragma unroll
      for (int fi = 0; fi < 4; ++fi)
#pragma unroll
        for (int r = 0; r < 4; ++r) acc[fi][fj][r] += bias;
    }

    if (j < 2) {
      int h = j * 4 + w;
      float t4[4][4];
#pragma unroll
      for (int fi = 0; fi < 4; ++fi)
#pragma unroll
        for (int r = 0; r < 4; ++r) {
          float s = 0.f;
#pragma unroll
          for (int fj = 0; fj < 4; ++fj) { float v = acc[fi][fj][r]; s += v * v; }
          t4[fi][r] = s;
        }
#pragma unroll
      for (int mask = 1; mask <= 8; mask <<= 1)
#pragma unroll
        for (int fi = 0; fi < 4; ++fi)
#pragma unroll
          for (int r = 0; r < 4; ++r)
            t4[fi][r] += __shfl_xor(t4[fi][r], mask, 64);
      if (li == 0) {
#pragma unroll
        for (int fi = 0; fi < 4; ++fi)
#pragma unroll
          for (int r = 0; r < 4; ++r)
            diag_s[h * 64 + fi * 16 + g * 4 + r] = 0.5f * t4[fi][r];
      }
    } else {
      // ddk -> phi_k transposed [m][tok] in padded scratch, then [h*32+m][n]
#pragma unroll
      for (int hp = 0; hp < 2; ++hp) {
        int h = w * 2 + hp;
#pragma unroll
        for (int fj2 = 0; fj2 < 2; ++fj2) {
          int m = fj2 * 16 + li;
          bool valid = (m < 30);
#pragma unroll
          for (int fi = 0; fi < 4; ++fi)
#pragma unroll
            for (int r = 0; r < 4; ++r) {
              int tok = fi * 16 + g * 4 + r;
              float ph = valid
                  ? (RATIO * __expf(acc[fi][hp * 2 + fj2][r] - diag_s[h * 64 + tok]) + REPS)
                  : 0.0f;
              *reinterpret_cast<unsigned short*>(scr + m * 144 + tok * 2) = f2b(ph);
            }
        }
        int mrow = l >> 1, half = l & 1;
        size_t gbase = ((size_t)(h * 32 + mrow)) * 65536 + n0 + half * 32;
#pragma unroll
        for (int i = 0; i < 4; ++i) {
          us8 o = *reinterpret_cast<const us8*>(scr + mrow * 144 + half * 64 + i * 16);
          *reinterpret_cast<us8*>(&phikT[gbase + i * 8]) = o;
        }
      }
    }
  }
}

// ---------------- K2: LDS-free partial S2 = phi_k^T @ x ----------------
__global__ __launch_bounds__(256) void k_S(
    const unsigned short* __restrict__ phikT, const unsigned short* __restrict__ xbfT,
    float* __restrict__ S2, float* __restrict__ ksum) {
  int tid = threadIdx.x;
  int w = tid >> 6, l = tid & 63, g = l >> 4, li = l & 15;
  int bid = blockIdx.x;
  int bh = bid >> 3, chunk = bid & 7;
  int b = bh >> 3, h = bh & 7;
  int t00 = b * 4096 + chunk * 512;

  const short* pk = reinterpret_cast<const short*>(phikT);
  const short* xt = reinterpret_cast<const short*>(xbfT);
  size_t arow0 = ((size_t)(h * 32 + li)) * 65536 + t00;
  size_t arow1 = ((size_t)(h * 32 + 16 + li)) * 65536 + t00;
  size_t brow0 = ((size_t)(w * 32 + li)) * 65536 + t00;
  size_t brow1 = ((size_t)(w * 32 + 16 + li)) * 65536 + t00;

  float s0 = 0.f, s1 = 0.f;
  f32x4 acc[2][2] = {};
#pragma unroll 2
  for (int tile = 0; tile < 8; ++tile) {
    int toff = tile * 64 + g * 8;
#pragma unroll
    for (int ks = 0; ks < 2; ++ks) {
      int t = toff + ks * 32;
      short8 a0 = *reinterpret_cast<const short8*>(pk + arow0 + t);
      short8 a1 = *reinterpret_cast<const short8*>(pk + arow1 + t);
      if (w == 0) {
#pragma unroll
        for (int e = 0; e < 8; ++e) {
          s0 += b2f((unsigned short)a0[e]);
          s1 += b2f((unsigned short)a1[e]);
        }
      }
      short8 b0 = *reinterpret_cast<const short8*>(xt + brow0 + t);
      short8 b1 = *reinterpret_cast<const short8*>(xt + brow1 + t);
      acc[0][0] = __builtin_amdgcn_mfma_f32_16x16x32_bf16(a0, b0, acc[0][0], 0, 0, 0);
      acc[1][0] = __builtin_amdgcn_mfma_f32_16x16x32_bf16(a1, b0, acc[1][0], 0, 0, 0);
      acc[0][1] = __builtin_amdgcn_mfma_f32_16x16x32_bf16(a0, b1, acc[0][1], 0, 0, 0);
      acc[1][1] = __builtin_amdgcn_mfma_f32_16x16x32_bf16(a1, b1, acc[1][1], 0, 0, 0);
    }
  }
  // store this block's partial (no atomics)
#pragma unroll
  for (int fm = 0; fm < 2; ++fm)
#pragma unroll
    for (int fc = 0; fc < 2; ++fc)
#pragma unroll
      for (int r = 0; r < 4; ++r) {
        int m = fm * 16 + g * 4 + r;
        int c = w * 32 + fc * 16 + li;
        S2[(size_t)bid * 4096 + m * 128 + c] = acc[fm][fc][r];
      }
  // ksum from A-fragments (wave 0 only; reduce over g)
  s0 += __shfl_xor(s0, 16, 64); s0 += __shfl_xor(s0, 32, 64);
  s1 += __shfl_xor(s1, 16, 64); s1 += __shfl_xor(s1, 32, 64);
  if (w == 0 && l < 16) {
    atomicAdd(&ksum[bh * 32 + l], s0);
    atomicAdd(&ksum[bh * 32 + 16 + l], s1);
  }
}

// ---------------- K3: sum partials; kvs = S@Wv^T + ksum*bv; Gt = kvs@Wo^T ----------------
__global__ __launch_bounds__(256) void k_fold(
    const float* __restrict__ S2, const float* __restrict__ wv,
    const float* __restrict__ bv, const float* __restrict__ wo,
    const float* __restrict__ ksum, unsigned short* __restrict__ Gt) {
  __shared__ float ss[32 * 128];
  __shared__ float wvs[64 * 128];  // [d][c]
  __shared__ float kvl[32 * 64];   // [m][d]
  __shared__ float wos[64 * 64];   // [d][c']
  __shared__ float bvs[64];
  __shared__ float kss[32];
  int tid = threadIdx.x;
  int bh = blockIdx.x, h = bh & 7;
  for (int i = tid; i < 4096; i += 256) {
    float a = 0.f;
#pragma unroll
    for (int c = 0; c < 8; ++c) a += S2[(size_t)(bh * 8 + c) * 4096 + i];
    ss[i] = a;
  }
  for (int i = tid; i < 8192; i += 256) wvs[i] = wv[(size_t)h * 8192 + i];
  {
    int c = tid >> 2, dseg = tid & 3;
#pragma unroll
    for (int jj = 0; jj < 16; ++jj) {
      int d = dseg * 16 + jj;
      wos[d * 64 + c] = wo[c * 512 + h * 64 + d];
    }
  }
  if (tid < 64) bvs[tid] = bv[h * 64 + tid];
  if (tid < 32) kss[tid] = ksum[bh * 32 + tid];
  __syncthreads();
  {
    int m = tid >> 3, dg = tid & 7;
#pragma unroll
    for (int i = 0; i < 8; ++i) {
      int d = dg * 8 + i;
      float a = kss[m] * bvs[d];
      for (int c = 0; c < 128; ++c) a += ss[m * 128 + c] * wvs[d * 128 + c];
      kvl[m * 64 + d] = a;
    }
  }
  __syncthreads();
  int cp = tid & 63, mseg = tid >> 6;
  us8 outv;
#pragma unroll
  for (int jj = 0; jj < 8; ++jj) {
    int m = mseg * 8 + jj;
    float a = 0.f;
    for (int d = 0; d < 64; ++d) a += kvl[m * 64 + d] * wos[d * 64 + cp];
    outv[jj] = f2b(a);
  }
  *reinterpret_cast<us8*>(Gt + ((size_t)bh * 64 + cp) * 32 + mseg * 8) = outv;
}

// ---------------- K4: fused q-GEMM + phi_q + out ----------------
__global__ __launch_bounds__(256) void k_out(
    const unsigned short* __restrict__ xbf, const unsigned short* __restrict__ wqkv,
    const float* __restrict__ wbp, const unsigned short* __restrict__ Gt,
    const float* __restrict__ ksum, const float* __restrict__ wob,
    float* __restrict__ out) {
  __shared__ unsigned short xs[64 * 128];    // 16KB
  __shared__ unsigned short phiqs[8 * 2048]; // 32KB: [h][64 tok][32 m] swizzled
  __shared__ float diag_s[512];              // [h*64 + tok]

  int tid = threadIdx.x;
  int w = tid >> 6, l = tid & 63;
  int g = l >> 4, li = l & 15;
  int n0 = blockIdx.x * 64;
  int b = n0 >> 12;

  {
    int row = tid >> 2, seg = tid & 3;
    const unsigned short* src = xbf + (size_t)(n0 + row) * 128 + seg * 32;
#pragma unroll
    for (int q8 = 0; q8 < 4; ++q8) {
      us8 o = *reinterpret_cast<const us8*>(src + q8 * 8);
      int byte = (row * 256 + seg * 64 + q8 * 16) ^ ((row & 7) << 4);
      *reinterpret_cast<us8*>(((char*)xs) + byte) = o;
    }
  }
  __syncthreads();

  const short* wq_s = reinterpret_cast<const short*>(wqkv);

  for (int j = 0; j < 3; ++j) {
    if (j == 2) __syncthreads();   // diag complete before ddq
    int bcol = (j < 2) ? (j * 256 + w * 64) : (1024 + w * 64);

    f32x4 acc[4][4] = {};
#pragma unroll
    for (int ks = 0; ks < 4; ++ks) {
      short8 a[4], bb[4];
#pragma unroll
      for (int fi = 0; fi < 4; ++fi) {
        int tokl = fi * 16 + li;
        int byte = (tokl * 256 + (ks * 32 + g * 8) * 2) ^ ((tokl & 7) << 4);
        a[fi] = *reinterpret_cast<const short8*>(((const char*)xs) + byte);
      }
#pragma unroll
      for (int fj = 0; fj < 4; ++fj)
        bb[fj] = *reinterpret_cast<const short8*>(wq_s + (bcol + fj * 16 + li) * 128 + ks * 32 + g * 8);
#pragma unroll
      for (int fi = 0; fi < 4; ++fi)
#pragma unroll
        for (int fj = 0; fj < 4; ++fj)
          acc[fi][fj] = __builtin_amdgcn_mfma_f32_16x16x32_bf16(a[fi], bb[fj], acc[fi][fj], 0, 0, 0);
    }
#pragma unroll
    for (int fj = 0; fj < 4; ++fj) {
      float bias = wbp[bcol + fj * 16 + li];
#pragma unroll
      for (int fi = 0; fi < 4; ++fi)
#pragma unroll
        for (int r = 0; r < 4; ++r) acc[fi][fj][r] += bias;
    }

    if (j < 2) {
      int h = j * 4 + w;
      float t4[4][4];
#pragma unroll
      for (int fi = 0; fi < 4; ++fi)
#pragma unroll
        for (int r = 0; r < 4; ++r) {
          float s = 0.f;
#pragma unroll
          for (int fj = 0; fj < 4; ++fj) { float v = acc[fi][fj][r]; s += v * v; }
          t4[fi][r] = s;
        }
#pragma unroll
      for (int mask = 1; mask <= 8; mask <<= 1)
#pragma unroll
        for (int fi = 0; fi < 4; ++fi)
#pragma unroll
          for (int r = 0; r < 4; ++r)
            t4[fi][r] += __shfl_xor(t4[fi][r], mask, 64);
      if (li == 0) {
#pragma unroll
        for (int fi = 0; fi < 4; ++fi)
#pragma unroll
          for (int r = 0; r < 4; ++r)
            diag_s[h * 64 + fi * 16 + g * 4 + r] = 0.5f * t4[fi][r];
      }
    } else {
      // ddq -> phi_q for heads 2w, 2w+1 into phiqs
#pragma unroll
      for (int hp = 0; hp < 2; ++hp) {
        int h = w * 2 + hp;
        char* st = ((char*)phiqs) + h * 4096;
#pragma unroll
        for (int fj2 = 0; fj2 < 2; ++fj2) {
          int m = fj2 * 16 + li;
          bool valid = (m < 30);
#pragma unroll
          for (int fi = 0; fi < 4; ++fi)
#pragma unroll
            for (int r = 0; r < 4; ++r) {
              int tok = fi * 16 + g * 4 + r;
              float ph = valid
                  ? (RATIO * __expf(acc[fi][hp * 2 + fj2][r] - diag_s[h * 64 + tok]) + REPS)
                  : 0.0f;
              int byte = (tok * 64 + m * 2) ^ ((tok & 7) << 4);
              *reinterpret_cast<unsigned short*>(st + byte) = f2b(ph);
            }
        }
      }
    }
  }
  __syncthreads();   // phiqs complete

  const short* gt_s = reinterpret_cast<const short*>(Gt);
  int tokl = w * 16 + li;
  f32x4 oacc[4] = {};
#pragma unroll
  for (int h = 0; h < 8; ++h) {
    int bh = b * 8 + h;
    int abyte = h * 4096 + ((tokl * 64 + g * 16) ^ ((tokl & 7) << 4));
    short8 a = *reinterpret_cast<const short8*>(((const char*)phiqs) + abyte);
    const float* ksrow = ksum + bh * 32 + g * 8;
    float den = 0.f;
#pragma unroll
    for (int jj = 0; jj < 8; ++jj) den += b2f((unsigned short)a[jj]) * ksrow[jj];
    den += __shfl_xor(den, 16, 64);
    den += __shfl_xor(den, 32, 64);
    float rd = 1.0f / den;
    f32x4 nm[4];
#pragma unroll
    for (int fj = 0; fj < 4; ++fj) {
      short8 bb = *reinterpret_cast<const short8*>(gt_s + ((size_t)bh * 64 + fj * 16 + li) * 32 + g * 8);
      f32x4 z = {};
      nm[fj] = __builtin_amdgcn_mfma_f32_16x16x32_bf16(a, bb, z, 0, 0, 0);
    }
#pragma unroll
    for (int r = 0; r < 4; ++r) {
      float rdr = __shfl(rd, g * 4 + r, 64);
#pragma unroll
      for (int fj = 0; fj < 4; ++fj) oacc[fj][r] += nm[fj][r] * rdr;
    }
  }
#pragma unroll
  for (int fj = 0; fj < 4; ++fj) {
    float bias = wob[fj * 16 + li];
#pragma unroll
    for (int r = 0; r < 4; ++r) {
      int n = n0 + w * 16 + g * 4 + r;
      out[(size_t)n * 64 + fj * 16 + li] = oacc[fj][r] + bias;
    }
  }
}

extern "C" void kernel_launch(void* const* d_in, const int* in_sizes, int n_in,
                              void* d_out, int out_size, void* d_ws, size_t ws_size,
                              hipStream_t stream) {
  const int expect[10] = {8388608, 65536, 512, 65536, 512, 65536, 512, 32768, 64, 1920};
  if (n_in != 10) return;
  for (int i = 0; i < 10; ++i) if (in_sizes[i] != expect[i]) return;
  if (out_size != 4194304) return;
  if (ws_size < WS_NEED) return;

  const float* x    = (const float*)d_in[0];
  const float* wq   = (const float*)d_in[1];
  const float* bq   = (const float*)d_in[2];
  const float* wk   = (const float*)d_in[3];
  const float* bk   = (const float*)d_in[4];
  const float* wv   = (const float*)d_in[5];
  const float* bv   = (const float*)d_in[6];
  const float* wo   = (const float*)d_in[7];
  const float* wob  = (const float*)d_in[8];
  const float* proj = (const float*)d_in[9];

  char* ws = (char*)d_ws;
  unsigned short* wqkv  = (unsigned short*)(ws + OF_WQKV);
  float*          wbp   = (float*)(ws + OF_WBP);
  unsigned short* xbf   = (unsigned short*)(ws + OF_XBF);
  unsigned short* xbfT  = (unsigned short*)(ws + OF_XBFT);
  unsigned short* phikT = (unsigned short*)(ws + OF_PHIKT);
  float*          S2    = (float*)(ws + OF_S2);
  float*          ksum  = (float*)(ws + OF_KSUM);
  unsigned short* Gt    = (unsigned short*)(ws + OF_GT);

  (void)hipMemsetAsync(ws + OF_KSUM, 0, 16384, stream);

  k_pack<<<529, 256, 0, stream>>>(wq, wk, bq, bk, proj, wqkv, wbp);
  k_xconv<<<1024, 256, 0, stream>>>(x, xbf, xbfT);
  k_qkv<<<1024, 256, 0, stream>>>(xbf, wqkv, wbp, phikT);
  k_S<<<1024, 256, 0, stream>>>(phikT, xbfT, S2, ksum);
  k_fold<<<128, 256, 0, stream>>>(S2, wv, bv, wo, ksum, Gt);
  k_out<<<1024, 256, 0, stream>>>(xbf, wqkv, wbp, Gt, ksum, wob, (float*)d_out);
}